// Round 10
// baseline (1006.706 us; speedup 1.0000x reference)
//
#include <hip/hip_runtime.h>
#include <math.h>

#define NROWS 8192
#define DIM   64
#define KSEL  32
#define NQ    (NROWS - KSEL)   /* 8160 query rows */
#define QPB   64               /* queries per block = 1 wave */
#define NQB   128              /* ceil(NQ / QPB) */

// ---------------------------------------------------------------------------
// Kernel A: row norms replicating XLA:CPU (LLVM-vectorized fused reduce):
//   VF=8 lanes, init 0, per-lane FMA chain, horizontal shuffle-tree
//   ((r0+r4)+(r2+r6)) + ((r1+r5)+(r3+r7)).   [validated bit-exact R8/R9]
// ---------------------------------------------------------------------------
__global__ void norms_kernel(const float* __restrict__ x, float* __restrict__ sq) {
    int j = blockIdx.x * blockDim.x + threadIdx.x;
    if (j >= NROWS) return;
    const float* xr = x + (size_t)j * DIM;
    float r[8];
#pragma unroll
    for (int u = 0; u < 8; ++u) r[u] = 0.0f;
#pragma unroll
    for (int i = 0; i < DIM; i += 8) {
#pragma unroll
        for (int u = 0; u < 8; ++u)
            r[u] = __fmaf_rn(xr[i + u], xr[i + u], r[u]);
    }
    const float s04 = __fadd_rn(r[0], r[4]);
    const float s26 = __fadd_rn(r[2], r[6]);
    const float s15 = __fadd_rn(r[1], r[5]);
    const float s37 = __fadd_rn(r[3], r[7]);
    sq[j] = __fadd_rn(__fadd_rn(s04, s26), __fadd_rn(s15, s37));
}

// ---------------------------------------------------------------------------
// Per-lane 32-entry max-heap of u64 keys in LDS (stride 33).
// Keeps the 32 SMALLEST keys; root (tau) = largest kept.  Precondition k < tau.
// ---------------------------------------------------------------------------
__device__ inline void heap_insert(unsigned long long* H, unsigned long long k,
                                   unsigned long long& tau) {
    unsigned i = 0;
    while (true) {
        const unsigned l = 2 * i + 1;
        if (l >= KSEL) break;
        const unsigned rr = l + 1;
        unsigned long long cb = H[l];
        unsigned bi = l;
        if (rr < KSEL) {
            const unsigned long long cr = H[rr];
            if (cr > cb) { cb = cr; bi = rr; }
        }
        if (cb > k) {
            H[i] = cb;
            if (i == 0) tau = cb;
            i = bi;
        } else break;
    }
    H[i] = k;
    if (i == 0) tau = k;
}

// ---------------------------------------------------------------------------
// Kernel B: distance + streaming per-lane top-32.
// Grid (NQB, maxc).  Block = 1 wave.  Lane owns query r = 32 + 64*qb + lane.
// Candidate j is wave-uniform (broadcast loads).  Dot = bit-exact sequential
// FMA chain (d=0..63), 4 candidates in flight (ILP-4).
// ---------------------------------------------------------------------------
__global__ __launch_bounds__(QPB)
void dist_kernel(const float* __restrict__ x, const float* __restrict__ sq,
                 unsigned long long* __restrict__ partial,
                 int chunk, int maxc) {
    const int qb   = blockIdx.x;
    const int c    = blockIdx.y;
    const int lane = threadIdx.x;

    const int r_hi = min(32 + (qb + 1) * QPB, NROWS);   // exclusive cap
    const int jbeg = c * chunk;
    if (jbeg >= r_hi) return;                            // no lane needs this chunk
    const int jend = min(jbeg + chunk, r_hi);            // both multiples of 4

    const int  r_raw = 32 + qb * QPB + lane;
    const bool vq    = (r_raw < NROWS);
    const int  r     = vq ? r_raw : 0;                   // r=0 => never accepts
    const int  qrow  = vq ? r_raw : 0;

    __shared__ unsigned long long heap[QPB * 33];
    unsigned long long* H = heap + lane * 33;
#pragma unroll
    for (int s = 0; s < KSEL; ++s) H[s] = ~0ull;
    unsigned long long tau = ~0ull;

    // Per-lane query row into registers
    float q[DIM];
    const float4* q4 = reinterpret_cast<const float4*>(x + (size_t)qrow * DIM);
#pragma unroll
    for (int i = 0; i < DIM / 4; ++i) {
        float4 v = q4[i];
        q[4 * i + 0] = v.x; q[4 * i + 1] = v.y;
        q[4 * i + 2] = v.z; q[4 * i + 3] = v.w;
    }
    const float sqr = sq[qrow];

    // Candidate stream, 4 per step (independent seq-FMA chains = ILP 4)
    for (int j0 = jbeg; j0 < jend; j0 += 4) {
        const float* c0 = x + (size_t)j0 * DIM;
        float a0 = 0.0f, a1 = 0.0f, a2 = 0.0f, a3 = 0.0f;
#pragma unroll
        for (int d = 0; d < DIM; ++d) {
            const float qd = q[d];
            a0 = __fmaf_rn(qd, c0[d], a0);
            a1 = __fmaf_rn(qd, c0[d + DIM], a1);
            a2 = __fmaf_rn(qd, c0[d + 2 * DIM], a2);
            a3 = __fmaf_rn(qd, c0[d + 3 * DIM], a3);
        }
        const float s0 = sq[j0], s1 = sq[j0 + 1], s2 = sq[j0 + 2], s3 = sq[j0 + 3];
        const float d0 = fmaxf(__fsub_rn(__fadd_rn(sqr, s0), __fmul_rn(2.0f, a0)), 0.0f);
        const float d1 = fmaxf(__fsub_rn(__fadd_rn(sqr, s1), __fmul_rn(2.0f, a1)), 0.0f);
        const float d2 = fmaxf(__fsub_rn(__fadd_rn(sqr, s2), __fmul_rn(2.0f, a2)), 0.0f);
        const float d3 = fmaxf(__fsub_rn(__fadd_rn(sqr, s3), __fmul_rn(2.0f, a3)), 0.0f);
        const unsigned long long k0 =
            ((unsigned long long)__float_as_uint(d0) << 32) | (unsigned)j0;
        const unsigned long long k1 =
            ((unsigned long long)__float_as_uint(d1) << 32) | (unsigned)(j0 + 1);
        const unsigned long long k2 =
            ((unsigned long long)__float_as_uint(d2) << 32) | (unsigned)(j0 + 2);
        const unsigned long long k3 =
            ((unsigned long long)__float_as_uint(d3) << 32) | (unsigned)(j0 + 3);
        if (j0 < r && k0 < tau)     heap_insert(H, k0, tau);
        if (j0 + 1 < r && k1 < tau) heap_insert(H, k1, tau);
        if (j0 + 2 < r && k2 < tau) heap_insert(H, k2, tau);
        if (j0 + 3 < r && k3 < tau) heap_insert(H, k3, tau);
    }

    // Write partial top-32 for (query, chunk)
    if (vq) {
        const int qi = r_raw - KSEL;
        unsigned long long* dst = partial + ((size_t)qi * maxc + c) * KSEL;
#pragma unroll
        for (int s = 0; s < KSEL; ++s) dst[s] = H[s];
    }
}

// ---------------------------------------------------------------------------
// Kernel C: merge per-chunk partials -> exact global top-32 per query.
// 256 threads per query block; handles up to 2048 partial entries.
// u64-min keys = ascending (dist, index), low-index ties.
// ---------------------------------------------------------------------------
__global__ __launch_bounds__(256)
void merge_kernel(const unsigned long long* __restrict__ partial,
                  int chunk, int maxc,
                  float* __restrict__ out_d, float* __restrict__ out_i) {
    const int qi  = blockIdx.x;     // 0..8159
    const int rr  = qi + KSEL;
    const int tid = threadIdx.x;
    const int nc  = (rr + chunk - 1) / chunk;
    const int ne  = nc * KSEL;      // <= 2048

    __shared__ unsigned long long red[4];

    const unsigned long long* src = partial + (size_t)qi * maxc * KSEL;
    unsigned long long e[8];
#pragma unroll
    for (int s = 0; s < 8; ++s) {
        const int idx = s * 256 + tid;
        e[s] = (idx < ne) ? src[idx] : ~0ull;
    }
    unsigned long long pmin = ~0ull;
#pragma unroll
    for (int s = 0; s < 8; ++s) pmin = e[s] < pmin ? e[s] : pmin;

    for (int it = 0; it < KSEL; ++it) {
        unsigned long long v = pmin;
#pragma unroll
        for (int off = 32; off > 0; off >>= 1) {
            const unsigned long long o = __shfl_down(v, off, 64);
            v = o < v ? o : v;
        }
        if ((tid & 63) == 0) red[tid >> 6] = v;
        __syncthreads();
        unsigned long long g = red[0];
#pragma unroll
        for (int w = 1; w < 4; ++w) g = red[w] < g ? red[w] : g;

        if (tid == 0) {
            out_d[(size_t)qi * KSEL + it] = __uint_as_float((unsigned)(g >> 32));
            out_i[(size_t)qi * KSEL + it] = (float)(unsigned)(g & 0xFFFFFFFFu);
        }
        if (pmin == g) {   // unique winner (keys embed unique j)
#pragma unroll
            for (int s = 0; s < 8; ++s) if (e[s] == g) e[s] = ~0ull;
            pmin = ~0ull;
#pragma unroll
            for (int s = 0; s < 8; ++s) pmin = e[s] < pmin ? e[s] : pmin;
        }
        __syncthreads();   // red[] reuse
    }
}

extern "C" void kernel_launch(void* const* d_in, const int* in_sizes, int n_in,
                              void* d_out, int out_size, void* d_ws, size_t ws_size,
                              hipStream_t stream) {
    const float* x = (const float*)d_in[0];    // anchor_x [8192, 64] fp32
    float* sq = (float*)d_ws;                  // 8192 floats
    unsigned long long* partial =
        (unsigned long long*)((char*)d_ws + 32768);
    float* out_d = (float*)d_out;              // [8160, 32] distances
    float* out_i = out_d + (size_t)NQ * KSEL;  // [8160, 32] indices (as fp32)

    // Smallest chunk (most parallelism) whose scratch fits ws_size.
    int chunk = NROWS;
    for (int c = 256; c <= NROWS; c <<= 1) {
        const size_t need = 32768 + (size_t)NQ * (NROWS / c) * KSEL * 8;
        if (need <= ws_size) { chunk = c; break; }
    }
    const int maxc = NROWS / chunk;

    norms_kernel<<<NROWS / 256, 256, 0, stream>>>(x, sq);
    dim3 grid(NQB, maxc);
    dist_kernel<<<grid, QPB, 0, stream>>>(x, sq, partial, chunk, maxc);
    merge_kernel<<<NQ, 256, 0, stream>>>(partial, chunk, maxc, out_d, out_i);
}